// Round 8
// baseline (379.675 us; speedup 1.0000x reference)
//
#include <hip/hip_runtime.h>
#include <hip/hip_bf16.h>
#include <math.h>

#define NE 80000
#define NN 10000
#define NG 16
#define MP_NORM 0.31622776601683794f   // 1/sqrt(10)
#define RBF_NORM 0.60302268915552724f  // sqrt(2/5.5)

// monomial tables: index -> (lx,ly,lz), l
__constant__ int c_mx[20] = {0, 1,0,0, 2,1,1,0,0,0, 3,2,2,1,1,1,0,0,0,0};
__constant__ int c_my[20] = {0, 0,1,0, 0,1,0,2,1,0, 0,1,0,2,1,0,3,2,1,0};
__constant__ int c_mz[20] = {0, 0,0,1, 0,0,1,0,1,2, 0,0,1,0,1,2,0,1,2,3};

__device__ __forceinline__ int l_of_a(int a) {
    return (a >= 10) ? 3 : ((a >= 4) ? 2 : ((a >= 1) ? 1 : 0));
}

// async global->LDS, 4 bytes per lane; dest = uniform base + lane*4
__device__ __forceinline__ void gl_lds4(const float* g, float* l) {
    __builtin_amdgcn_global_load_lds(
        (const __attribute__((address_space(1))) unsigned int*)g,
        (__attribute__((address_space(3))) unsigned int*)l, 4, 0, 0);
}

// symmetrize one node's 1080-vector (in LDS) -> 324 outputs (global row)
__device__ __forceinline__ void symm_from_lds(const float* Als, float* brow,
                                              int lane) {
    if (lane >= 54) return;
    const int s2 = lane / 9, c = lane - s2 * 9;
    const float* a = Als + s2 * 180 + c;
    float v[20];
    #pragma unroll
    for (int i = 0; i < 20; i++) v[i] = a[i * 9];
    const float o0 = v[0];
    const float o1 = v[1]*v[1] + v[2]*v[2] + v[3]*v[3];
    const float o2 = v[4]*v[4] + 2.f*v[5]*v[5] + 2.f*v[6]*v[6]
                   + v[7]*v[7] + 2.f*v[8]*v[8] + v[9]*v[9];
    const float o3 = v[10]*v[10] + 3.f*v[11]*v[11] + 3.f*v[12]*v[12]
                   + 3.f*v[13]*v[13] + 6.f*v[14]*v[14] + 3.f*v[15]*v[15]
                   + v[16]*v[16] + 3.f*v[17]*v[17] + 3.f*v[18]*v[18] + v[19]*v[19];
    const float o4 = v[1]*v[1]*v[4] + 2.f*v[1]*v[2]*v[5] + 2.f*v[1]*v[3]*v[6]
                   + 2.f*v[2]*v[1]*v[5] + v[2]*v[2]*v[7] + 2.f*v[2]*v[3]*v[8]
                   + 2.f*v[3]*v[1]*v[6] + 2.f*v[3]*v[2]*v[8] + v[3]*v[3]*v[9];
    const float o5 =
        v[1]*(v[4]*v[10] + 3.f*v[5]*v[11] + 3.f*v[6]*v[12] + 3.f*v[7]*v[13]
              + 6.f*v[8]*v[14] + 3.f*v[9]*v[15])
      + v[2]*(3.f*v[4]*v[11] + 3.f*v[5]*v[13] + 6.f*v[6]*v[14] + v[7]*v[16]
              + 3.f*v[8]*v[17] + 3.f*v[9]*v[18])
      + v[3]*(3.f*v[4]*v[12] + 6.f*v[5]*v[14] + 3.f*v[6]*v[15] + 3.f*v[7]*v[17]
              + 3.f*v[8]*v[18] + v[9]*v[19]);
    float* b = brow + s2 * 54 + c;
    b[0]  = o0;
    b[9]  = o1;
    b[18] = o2;
    b[27] = o3;
    b[36] = o4;
    b[45] = o5;
}

// ---------------------------------------------------------------------------
// CSR build: histogram of dst over fc-active edges, scan, fill.
// ---------------------------------------------------------------------------
__global__ __launch_bounds__(256) void k_hist(
    const float* __restrict__ pos, const int* __restrict__ src,
    const int* __restrict__ dst, const float* __restrict__ shifts,
    int* __restrict__ indeg)
{
    const int e = blockIdx.x * 256 + threadIdx.x;
    if (e >= NE) return;
    const int sn = src[e], dn = dst[e];
    const float vx = pos[3*dn+0] - pos[3*sn+0] + shifts[3*e+0];
    const float vy = pos[3*dn+1] - pos[3*sn+1] + shifts[3*e+1];
    const float vz = pos[3*dn+2] - pos[3*sn+2] + shifts[3*e+2];
    const float r = sqrtf(vx*vx + vy*vy + vz*vz) + 1e-9f;
    if (r * (1.0f / 5.5f) < 1.0f) atomicAdd(&indeg[dn], 1);
}

__global__ __launch_bounds__(256) void k_scan(const int* __restrict__ indeg,
                                              int* __restrict__ offs)
{
    __shared__ int part[256];
    const int t = threadIdx.x;
    int s = 0;
    for (int i = t * 40; i < t * 40 + 40; i++)
        if (i < NN) s += indeg[i];
    part[t] = s;
    __syncthreads();
    if (t == 0) {
        int run = 0;
        for (int i = 0; i < 256; i++) { int v = part[i]; part[i] = run; run += v; }
    }
    __syncthreads();
    int run = part[t];
    for (int i = t * 40; i < t * 40 + 40; i++) {
        if (i < NN) { offs[i] = run; run += indeg[i]; }
    }
}

__global__ __launch_bounds__(256) void k_fill(
    const float* __restrict__ pos, const int* __restrict__ src,
    const int* __restrict__ dst, const float* __restrict__ shifts,
    const int* __restrict__ offs, int* __restrict__ cursor,
    int* __restrict__ elist)
{
    const int e = blockIdx.x * 256 + threadIdx.x;
    if (e >= NE) return;
    const int sn = src[e], dn = dst[e];
    const float vx = pos[3*dn+0] - pos[3*sn+0] + shifts[3*e+0];
    const float vy = pos[3*dn+1] - pos[3*sn+1] + shifts[3*e+1];
    const float vz = pos[3*dn+2] - pos[3*sn+2] + shifts[3*e+2];
    const float r = sqrtf(vx*vx + vy*vy + vz*vz) + 1e-9f;
    if (r * (1.0f / 5.5f) < 1.0f) {
        const int p = offs[dn] + atomicAdd(&cursor[dn], 1);
        elist[p] = e;
    }
}

// ---------------------------------------------------------------------------
// Pass 1, gather form: one wave per node, one-edge-ahead prefetch of
// pos/shifts/ntype. Accumulate A[n] in registers, symmetrize inline -> B.
// ---------------------------------------------------------------------------
__global__ __launch_bounds__(64) void k_node1(
    const float* __restrict__ pos, const int* __restrict__ ntype,
    const int* __restrict__ srcArr, const float* __restrict__ shifts,
    const float* __restrict__ Wemb, const float* __restrict__ freqs,
    const float* __restrict__ W_rt, const int* __restrict__ offs,
    const int* __restrict__ indeg, const int* __restrict__ elist,
    float* __restrict__ A, float* __restrict__ Bf)
{
    __shared__ float eS[80];     // ang[0..19], code[20..28], radt[29..52]
    __shared__ float Als[1080];
    const int n = blockIdx.x, lane = threadIdx.x;
    int ridx[17], aidx[17], cidx[17];
    float acc[17];
    #pragma unroll
    for (int k = 0; k < 17; k++) {
        acc[k] = 0.f;
        const int i = lane + 64 * k;
        const int ii = (i < 1080) ? i : 0;
        const int s2 = ii / 180, rem = ii - s2 * 180;
        const int a = rem / 9, c = rem - a * 9;
        ridx[k] = 29 + l_of_a(a) * 6 + s2; aidx[k] = a; cidx[k] = 20 + c;
    }
    const float px = pos[3*n], py = pos[3*n+1], pz = pos[3*n+2];
    const float ed0 = Wemb[3*ntype[n]], ed1 = Wemb[3*ntype[n]+1],
                ed2 = Wemb[3*ntype[n]+2];
    float fr[6];
    #pragma unroll
    for (int q = 0; q < 6; q++) fr[q] = freqs[q];
    float wrt[6];
    if (lane >= 32 && lane < 56) {
        const int j = lane - 32, l = j / 6, s2 = j % 6;
        #pragma unroll
        for (int q = 0; q < 6; q++) wrt[q] = W_rt[(l*6 + q)*6 + s2];
    }
    const int e0 = offs[n], cnt = indeg[n];
    int e_n = 0, sn_n = 0, tn_n = 0;
    float pnx = 0, pny = 0, pnz = 0, snx = 0, sny = 0, snz = 0;
    if (cnt > 0) {
        e_n = elist[e0]; sn_n = srcArr[e_n]; tn_n = ntype[sn_n];
        pnx = pos[3*sn_n]; pny = pos[3*sn_n+1]; pnz = pos[3*sn_n+2];
        snx = shifts[3*e_n]; sny = shifts[3*e_n+1]; snz = shifts[3*e_n+2];
    }
    for (int t = 0; t < cnt; t++) {
        const int tn = tn_n;
        const float vx = px - pnx + snx;
        const float vy = py - pny + sny;
        const float vz = pz - pnz + snz;
        if (t + 1 < cnt) {
            e_n = elist[e0 + t + 1]; sn_n = srcArr[e_n]; tn_n = ntype[sn_n];
            pnx = pos[3*sn_n]; pny = pos[3*sn_n+1]; pnz = pos[3*sn_n+2];
            snx = shifts[3*e_n]; sny = shifts[3*e_n+1]; snz = shifts[3*e_n+2];
        }
        const float r = sqrtf(vx*vx + vy*vy + vz*vz) + 1e-9f;
        const float u = r * (1.0f / 5.5f);
        const float u2 = u*u, u3 = u2*u, u6 = u3*u3;
        const float fcv = 1.0f - 28.0f*u6 + 48.0f*u6*u - 21.0f*u6*u2;
        const float inv = 1.0f / r;
        float rb[6];
        #pragma unroll
        for (int q = 0; q < 6; q++)
            rb[q] = RBF_NORM * __sinf(r * fr[q]) * inv * fcv;
        if (lane < 20) {
            const float ux = vx*inv, uy = vy*inv, uz = vz*inv;
            const int lx = c_mx[lane], ly = c_my[lane], lz = c_mz[lane];
            float v = 1.f;
            for (int i = 0; i < lx; i++) v *= ux;
            for (int i = 0; i < ly; i++) v *= uy;
            for (int i = 0; i < lz; i++) v *= uz;
            eS[lane] = v;
        } else if (lane < 29) {
            const int c = lane - 20, m = c % 3;
            const float ed = (m == 0) ? ed0 : ((m == 1) ? ed1 : ed2);
            eS[lane] = Wemb[3*tn + c/3] * ed;
        } else if (lane >= 32 && lane < 56) {
            float s = 0.f;
            #pragma unroll
            for (int q = 0; q < 6; q++) s += rb[q] * wrt[q];
            eS[lane - 3] = s;
        }
        __syncthreads();
        #pragma unroll
        for (int k = 0; k < 17; k++)
            acc[k] += eS[ridx[k]] * eS[aidx[k]] * eS[cidx[k]];
        __syncthreads();
    }
    #pragma unroll
    for (int k = 0; k < 17; k++) {
        const int i = lane + 64 * k;
        if (i < 1080) { A[(long)n*1080 + i] = acc[k]; Als[i] = acc[k]; }
    }
    __syncthreads();
    symm_from_lds(Als, Bf + (long)n * 324, lane);
}

// chi[n,c'] = B[n,:] . W_chi[:,c']
__global__ __launch_bounds__(256) void k_chi(const float* __restrict__ Bf,
                                             const float* __restrict__ W_chi,
                                             float* __restrict__ chi)
{
    const int t = blockIdx.x * 256 + threadIdx.x;
    if (t >= NN * 9) return;
    const int cp = t % 9, n = t / 9;
    const float* b = Bf + (long)n * 324;
    float s = 0.f;
    #pragma unroll 4
    for (int j = 0; j < 324; j += 4) {
        const float4 bv = *(const float4*)(b + j);
        s += bv.x * W_chi[(j+0)*9 + cp] + bv.y * W_chi[(j+1)*9 + cp]
           + bv.z * W_chi[(j+2)*9 + cp] + bv.w * W_chi[(j+3)*9 + cp];
    }
    chi[t] = s;
}

// ---------------------------------------------------------------------------
// Pass 2, gather form with one-edge-ahead prefetch incl. A[src] row and chi.
// ---------------------------------------------------------------------------
__global__ __launch_bounds__(64) void k_node2(
    const float* __restrict__ pos, const int* __restrict__ ntype,
    const int* __restrict__ srcArr, const float* __restrict__ shifts,
    const float* __restrict__ Wemb, const float* __restrict__ freqs,
    const float* __restrict__ W_rt, const float* __restrict__ W_Ar,
    const float* __restrict__ W_mem, const int* __restrict__ offs,
    const int* __restrict__ indeg, const int* __restrict__ elist,
    const float* __restrict__ chi, const float* __restrict__ A,
    float* __restrict__ B2f)
{
    __shared__ float eS[80];     // ang, codechi[20..28], radtB[29..52], radtA[53..76]
    __shared__ float Als[1080];
    __shared__ float Qls[1080];
    __shared__ float Wm[144];
    const int n = blockIdx.x, lane = threadIdx.x;
    #pragma unroll
    for (int k = 0; k < 17; k++) {
        const int i = lane + 64 * k;
        if (i < 1080) Als[i] = A[(long)n*1080 + i];
    }
    Wm[lane] = W_mem[lane];
    Wm[lane + 64] = W_mem[lane + 64];
    if (lane < 16) Wm[lane + 128] = W_mem[lane + 128];
    int ridx[17], aidx[17], cidx[17];
    float acc[17];
    #pragma unroll
    for (int k = 0; k < 17; k++) {
        acc[k] = 0.f;
        const int i = lane + 64 * k;
        const int ii = (i < 1080) ? i : 0;
        const int s2 = ii / 180, rem = ii - s2 * 180;
        const int a = rem / 9, c = rem - a * 9;
        ridx[k] = 29 + l_of_a(a) * 6 + s2; aidx[k] = a; cidx[k] = 20 + c;
    }
    const float px = pos[3*n], py = pos[3*n+1], pz = pos[3*n+2];
    const float ed0 = Wemb[3*ntype[n]], ed1 = Wemb[3*ntype[n]+1],
                ed2 = Wemb[3*ntype[n]+2];
    float fr[6];
    #pragma unroll
    for (int q = 0; q < 6; q++) fr[q] = freqs[q];
    float wrtB[6], wrtA[6];
    if (lane >= 32 && lane < 56) {
        const int j = lane - 32, l = j / 6, s2 = j % 6;
        #pragma unroll
        for (int q = 0; q < 6; q++) {
            wrtB[q] = W_rt[(l*6 + q)*6 + s2];
            wrtA[q] = W_Ar[(l*6 + q)*6 + s2];
        }
    }
    __syncthreads();
    const int e0 = offs[n], cnt = indeg[n];
    int e_n = 0, sn_n = 0, tn_n = 0;
    float pnx = 0, pny = 0, pnz = 0, snx = 0, sny = 0, snz = 0, chin = 0.f;
    float an[17];
    #pragma unroll
    for (int k = 0; k < 17; k++) an[k] = 0.f;
    if (cnt > 0) {
        e_n = elist[e0]; sn_n = srcArr[e_n]; tn_n = ntype[sn_n];
        pnx = pos[3*sn_n]; pny = pos[3*sn_n+1]; pnz = pos[3*sn_n+2];
        snx = shifts[3*e_n]; sny = shifts[3*e_n+1]; snz = shifts[3*e_n+2];
        if (lane >= 20 && lane < 29) chin = chi[sn_n*9 + (lane - 20)];
        const float* ar = A + (long)sn_n * 1080;
        #pragma unroll
        for (int k = 0; k < 17; k++) {
            const int i = lane + 64 * k;
            if (i < 1080) an[k] = ar[i];
        }
    }
    for (int t = 0; t < cnt; t++) {
        const int tn = tn_n;
        const float chiv = chin;
        const float vx = px - pnx + snx;
        const float vy = py - pny + sny;
        const float vz = pz - pnz + snz;
        float av[17];
        #pragma unroll
        for (int k = 0; k < 17; k++) av[k] = an[k];
        if (t + 1 < cnt) {
            e_n = elist[e0 + t + 1]; sn_n = srcArr[e_n]; tn_n = ntype[sn_n];
            pnx = pos[3*sn_n]; pny = pos[3*sn_n+1]; pnz = pos[3*sn_n+2];
            snx = shifts[3*e_n]; sny = shifts[3*e_n+1]; snz = shifts[3*e_n+2];
            if (lane >= 20 && lane < 29) chin = chi[sn_n*9 + (lane - 20)];
            const float* ar = A + (long)sn_n * 1080;
            #pragma unroll
            for (int k = 0; k < 17; k++) {
                const int i = lane + 64 * k;
                if (i < 1080) an[k] = ar[i];
            }
        }
        const float r = sqrtf(vx*vx + vy*vy + vz*vz) + 1e-9f;
        const float u = r * (1.0f / 5.5f);
        const float u2 = u*u, u3 = u2*u, u6 = u3*u3;
        const float fcv = 1.0f - 28.0f*u6 + 48.0f*u6*u - 21.0f*u6*u2;
        const float inv = 1.0f / r;
        float rb[6];
        #pragma unroll
        for (int q = 0; q < 6; q++)
            rb[q] = RBF_NORM * __sinf(r * fr[q]) * inv * fcv;
        if (lane < 20) {
            const float ux = vx*inv, uy = vy*inv, uz = vz*inv;
            const int lx = c_mx[lane], ly = c_my[lane], lz = c_mz[lane];
            float v = 1.f;
            for (int i = 0; i < lx; i++) v *= ux;
            for (int i = 0; i < ly; i++) v *= uy;
            for (int i = 0; i < lz; i++) v *= uz;
            eS[lane] = v;
        } else if (lane < 29) {
            const int c = lane - 20, m = c % 3;
            const float ed = (m == 0) ? ed0 : ((m == 1) ? ed1 : ed2);
            eS[lane] = Wemb[3*tn + c/3] * ed * chiv;
        } else if (lane >= 32 && lane < 56) {
            float sB = 0.f, sA = 0.f;
            #pragma unroll
            for (int q = 0; q < 6; q++) { sB += rb[q]*wrtB[q]; sA += rb[q]*wrtA[q]; }
            eS[lane - 3]  = sB;
            eS[lane + 21] = sA;
        }
        __syncthreads();
        #pragma unroll
        for (int k = 0; k < 17; k++) {
            const int i = lane + 64 * k;
            if (i < 1080)
                acc[k] += eS[ridx[k]] * eS[aidx[k]] * eS[cidx[k]]
                        + av[k] * eS[ridx[k] + 24];
        }
        __syncthreads();
    }
    // memory term + MP_NORM -> Qls
    #pragma unroll
    for (int k = 0; k < 17; k++) {
        const int i = lane + 64 * k;
        if (i < 1080) {
            const int l6 = ridx[k] - 29;
            const int l = l6 / 6, s2v = l6 - 6 * l;
            const int rem = aidx[k] * 9 + (cidx[k] - 20);
            float m = 0.f;
            #pragma unroll
            for (int sp = 0; sp < 6; sp++)
                m += Als[sp*180 + rem] * Wm[l*36 + sp*6 + s2v];
            Qls[i] = acc[k] * MP_NORM + m;
        }
    }
    __syncthreads();
    symm_from_lds(Qls, B2f + (long)n * 324, lane);
}

// ---------------------------------------------------------------------------
// MLP readout v8: 64-node x 64-output GEMM tile per 256-thread block.
// K=648 in 24 chunks of 27, double-buffered LDS staged entirely via async
// global_load_lds (feat rows are per-lane gathers; W1 rows coalesced).
// One __syncthreads per chunk (its implicit vmcnt drain is the only wait).
// Inner loop: 2 broadcast ds_read_b128 + 16 FMA per kk per thread.
// ---------------------------------------------------------------------------
#define KC 27
__global__ __launch_bounds__(256) void k_mlp(
    const float* __restrict__ Bf, const float* __restrict__ B2f,
    const float* __restrict__ W1, const float* __restrict__ b1,
    const float* __restrict__ W2, const float* __restrict__ b2,
    const float* __restrict__ W3, const float* __restrict__ b3,
    const int* __restrict__ batch, float* __restrict__ out)
{
    __shared__ float As[2][KC][64];
    __shared__ float Ws[2][KC][64];
    __shared__ float h1T[64][65];
    __shared__ float W2L[2048];
    __shared__ float red[4][64];
    const int tid = threadIdx.x;
    const int lane = tid & 63;
    const int wq = tid >> 6;
    const int nb = blockIdx.x * 64;
    const int nlane = (nb + lane < NN) ? (nb + lane) : (NN - 1);  // clamp gather
    const int tx = tid & 15, ty = tid >> 4;

    // stage W2 (2048 floats) async: 32 row-loads, 8 per wave
    for (int i = wq; i < 32; i += 4)
        gl_lds4(W2 + i * 64 + lane, &W2L[i * 64]);

    // chunk ch: ch<12 -> Bf cols [27ch,27ch+27), W1 rows even;
    //           ch>=12 -> B2f cols [27(ch-12),...), W1 rows odd.
    // stage chunk into buffer b
    #define STAGE(ch, b)                                                       \
    {                                                                          \
        const int half_ = ((ch) >= 12) ? 1 : 0;                                \
        const int q0_ = ((ch) - 12 * half_) * KC;                              \
        const float* srcM_ = half_ ? B2f : Bf;                                 \
        for (int kk = wq; kk < KC; kk += 4) {                                  \
            gl_lds4(srcM_ + (size_t)nlane * 324 + q0_ + kk, &As[b][kk][0]);    \
            gl_lds4(W1 + (size_t)(2 * (q0_ + kk) + half_) * 64 + lane,         \
                    &Ws[b][kk][0]);                                            \
        }                                                                      \
    }

    STAGE(0, 0);
    __syncthreads();   // implicit vmcnt(0) drain: chunk 0 + W2L ready

    float acc[4][4] = {};
    int buf = 0;
    for (int ch = 0; ch < 24; ch++) {
        if (ch + 1 < 24) STAGE(ch + 1, buf ^ 1);
        #pragma unroll
        for (int kk = 0; kk < KC; kk++) {
            const float4 a = *(const float4*)&As[buf][kk][4 * ty - 16 * wq + 16 * wq]; // rows 4ty..4ty+3
            const float4 w = *(const float4*)&Ws[buf][kk][4 * tx];
            acc[0][0] += a.x * w.x; acc[0][1] += a.x * w.y;
            acc[0][2] += a.x * w.z; acc[0][3] += a.x * w.w;
            acc[1][0] += a.y * w.x; acc[1][1] += a.y * w.y;
            acc[1][2] += a.y * w.z; acc[1][3] += a.y * w.w;
            acc[2][0] += a.z * w.x; acc[2][1] += a.z * w.y;
            acc[2][2] += a.z * w.z; acc[2][3] += a.z * w.w;
            acc[3][0] += a.w * w.x; acc[3][1] += a.w * w.y;
            acc[3][2] += a.w * w.z; acc[3][3] += a.w * w.w;
        }
        __syncthreads();   // drains this wave's async loads; all waves done reading buf
        buf ^= 1;
    }

    // layer-1 bias + silu -> h1T[output][node]; thread covers nodes 4ty+i,
    // outputs 4tx+j
    const float4 bb = *(const float4*)&b1[4 * tx];
    #pragma unroll
    for (int i = 0; i < 4; i++) {
        float4 h;
        h.x = acc[i][0] + bb.x; h.y = acc[i][1] + bb.y;
        h.z = acc[i][2] + bb.z; h.w = acc[i][3] + bb.w;
        h.x = h.x / (1.f + __expf(-h.x)); h.y = h.y / (1.f + __expf(-h.y));
        h.z = h.z / (1.f + __expf(-h.z)); h.w = h.w / (1.f + __expf(-h.w));
        h1T[4*tx + 0][4*ty + i] = h.x;
        h1T[4*tx + 1][4*ty + i] = h.y;
        h1T[4*tx + 2][4*ty + i] = h.z;
        h1T[4*tx + 3][4*ty + i] = h.w;
    }
    __syncthreads();

    // layer 2: lane = node; wave wq owns outputs [8wq, 8wq+8). W2 from LDS.
    float acc2[8];
    #pragma unroll
    for (int j = 0; j < 8; j++) acc2[j] = b2[8*wq + j];
    #pragma unroll 4
    for (int k = 0; k < 64; k++) {
        const float hv = h1T[k][lane];
        const float4 wA = *(const float4*)&W2L[k*32 + 8*wq];
        const float4 wB = *(const float4*)&W2L[k*32 + 8*wq + 4];
        acc2[0] = fmaf(hv, wA.x, acc2[0]); acc2[1] = fmaf(hv, wA.y, acc2[1]);
        acc2[2] = fmaf(hv, wA.z, acc2[2]); acc2[3] = fmaf(hv, wA.w, acc2[3]);
        acc2[4] = fmaf(hv, wB.x, acc2[4]); acc2[5] = fmaf(hv, wB.y, acc2[5]);
        acc2[6] = fmaf(hv, wB.z, acc2[6]); acc2[7] = fmaf(hv, wB.w, acc2[7]);
    }
    // layer 3 partial over this wave's 8 outputs
    float part3 = 0.f;
    #pragma unroll
    for (int j = 0; j < 8; j++) {
        const float g = acc2[j] / (1.f + __expf(-acc2[j]));
        part3 += g * W3[8*wq + j];
    }
    red[wq][lane] = part3;
    __syncthreads();
    if (tid < 64 && nb + tid < NN) {
        const float tot = red[0][tid] + red[1][tid] + red[2][tid] + red[3][tid]
                        + b3[0];
        atomicAdd(out + batch[nb + tid], tot);
    }
    #undef STAGE
}

extern "C" void kernel_launch(void* const* d_in, const int* in_sizes, int n_in,
                              void* d_out, int out_size, void* d_ws, size_t ws_size,
                              hipStream_t stream)
{
    const float* pos    = (const float*)d_in[0];
    const int*   ntype  = (const int*)  d_in[1];
    const int*   src    = (const int*)  d_in[2];
    const int*   dst    = (const int*)  d_in[3];
    const float* shifts = (const float*)d_in[4];
    const int*   batch  = (const int*)  d_in[5];
    const float* Wemb   = (const float*)d_in[6];
    const float* freqs  = (const float*)d_in[7];
    const float* W_rt   = (const float*)d_in[8];
    const float* W_mem  = (const float*)d_in[9];
    const float* W_Ar   = (const float*)d_in[10];
    const float* W_chi  = (const float*)d_in[11];
    const float* W1     = (const float*)d_in[12];
    const float* b1     = (const float*)d_in[13];
    const float* W2     = (const float*)d_in[14];
    const float* b2     = (const float*)d_in[15];
    const float* W3     = (const float*)d_in[16];
    const float* b3     = (const float*)d_in[17];

    float* ws   = (float*)d_ws;
    float* A    = ws;                        // [NN,1080]
    float* Bf   = A   + (size_t)NN * 1080;   // [NN,324]
    float* B2f  = Bf  + (size_t)NN * 324;    // [NN,324]
    float* chi  = B2f + (size_t)NN * 324;    // [NN,9]
    int*   indeg  = (int*)(chi + (size_t)NN * 9);
    int*   offs   = indeg  + 10240;
    int*   cursor = offs   + 10240;
    int*   elist  = cursor + 10240;          // [NE]

    hipMemsetAsync(indeg,  0, 10240 * sizeof(int), stream);
    hipMemsetAsync(cursor, 0, 10240 * sizeof(int), stream);
    hipMemsetAsync(d_out,  0, (size_t)out_size * sizeof(float), stream);

    k_hist<<<(NE + 255)/256, 256, 0, stream>>>(pos, src, dst, shifts, indeg);
    k_scan<<<1, 256, 0, stream>>>(indeg, offs);
    k_fill<<<(NE + 255)/256, 256, 0, stream>>>(pos, src, dst, shifts, offs,
                                               cursor, elist);
    k_node1<<<NN, 64, 0, stream>>>(pos, ntype, src, shifts, Wemb, freqs, W_rt,
                                   offs, indeg, elist, A, Bf);
    k_chi<<<(NN*9 + 255)/256, 256, 0, stream>>>(Bf, W_chi, chi);
    k_node2<<<NN, 64, 0, stream>>>(pos, ntype, src, shifts, Wemb, freqs, W_rt,
                                   W_Ar, W_mem, offs, indeg, elist, chi, A, B2f);
    k_mlp<<<(NN + 63)/64, 256, 0, stream>>>(Bf, B2f, W1, b1, W2, b2, W3, b3,
                                            batch, (float*)d_out);
}